// Round 1
// baseline (4762.592 us; speedup 1.0000x reference)
//
#include <hip/hip_runtime.h>

constexpr int N = 4;
constexpr int C = 64;
constexpr int H = 256;
constexpr int W = 448;
constexpr int HW = H * W;

// One thread per source pixel. Splat 64 input channels (scaled by m=exp(metric))
// into d_out accumulators, and m itself into the norm buffer (d_ws).
__global__ void splat_kernel(const float* __restrict__ input,
                             const float* __restrict__ flow,
                             const float* __restrict__ metric,
                             float* __restrict__ out,    // N*C*HW accum (pre-zeroed)
                             float* __restrict__ norm)   // N*HW accum (pre-zeroed)
{
    int idx = blockIdx.x * blockDim.x + threadIdx.x;
    if (idx >= N * HW) return;
    int b = idx / HW;
    int p = idx - b * HW;
    int y = p / W;
    int x = p - y * W;

    float fx = (float)x + flow[(b * 2 + 0) * HW + p];
    float fy = (float)y + flow[(b * 2 + 1) * HW + p];
    float m  = __expf(metric[b * HW + p]);

    float x0f = floorf(fx), y0f = floorf(fy);
    int x0 = (int)x0f, y0 = (int)y0f;
    int x1 = x0 + 1,   y1 = y0 + 1;

    float wx1 = fx - x0f;        // weight toward x1
    float wx0 = 1.0f - wx1;      // = x1 - fx
    float wy1 = fy - y0f;
    float wy0 = 1.0f - wy1;

    bool vx0 = (x0 >= 0) & (x0 < W);
    bool vx1 = (x1 >= 0) & (x1 < W);
    bool vy0 = (y0 >= 0) & (y0 < H);
    bool vy1 = (y1 >= 0) & (y1 < H);

    bool vNW = vx0 & vy0, vNE = vx1 & vy0, vSW = vx0 & vy1, vSE = vx1 & vy1;
    float wNW = wx0 * wy0, wNE = wx1 * wy0, wSW = wx0 * wy1, wSE = wx1 * wy1;
    int iNW = y0 * W + x0, iNE = y0 * W + x1, iSW = y1 * W + x0, iSE = y1 * W + x1;

    // norm channel
    {
        float* nb = norm + b * HW;
        if (vNW) atomicAdd(nb + iNW, m * wNW);
        if (vNE) atomicAdd(nb + iNE, m * wNE);
        if (vSW) atomicAdd(nb + iSW, m * wSW);
        if (vSE) atomicAdd(nb + iSE, m * wSE);
    }

    const float* ib = input + (size_t)b * C * HW + p;
    float* ob = out + (size_t)b * C * HW;
#pragma unroll 4
    for (int c = 0; c < C; ++c) {
        float v = ib[(size_t)c * HW] * m;
        float* oc = ob + (size_t)c * HW;
        if (vNW) atomicAdd(oc + iNW, v * wNW);
        if (vNE) atomicAdd(oc + iNE, v * wNE);
        if (vSW) atomicAdd(oc + iSW, v * wSW);
        if (vSE) atomicAdd(oc + iSE, v * wSE);
    }
}

// In-place normalize: out[b][c][p] /= (norm[b][p] == 0 ? 1 : norm[b][p])
// float4-vectorized over pixels (HW % 4 == 0).
__global__ void norm_kernel(float* __restrict__ out,
                            const float* __restrict__ norm)
{
    int idx = blockIdx.x * blockDim.x + threadIdx.x;    // over N*C*HW/4
    int total = N * C * HW / 4;
    if (idx >= total) return;

    int pixq = idx % (HW / 4);          // which float4 within the image
    int bc   = idx / (HW / 4);          // fused b*C + c
    int b    = bc / C;

    const float4* np4 = (const float4*)(norm + (size_t)b * HW);
    float4 n = np4[pixq];
    n.x = (n.x == 0.0f) ? 1.0f : n.x;
    n.y = (n.y == 0.0f) ? 1.0f : n.y;
    n.z = (n.z == 0.0f) ? 1.0f : n.z;
    n.w = (n.w == 0.0f) ? 1.0f : n.w;

    float4* o4 = (float4*)out;
    float4 v = o4[idx];
    v.x /= n.x; v.y /= n.y; v.z /= n.z; v.w /= n.w;
    o4[idx] = v;
}

extern "C" void kernel_launch(void* const* d_in, const int* in_sizes, int n_in,
                              void* d_out, int out_size, void* d_ws, size_t ws_size,
                              hipStream_t stream)
{
    const float* input  = (const float*)d_in[0];   // (4,64,256,448)
    const float* flow   = (const float*)d_in[1];   // (4,2,256,448)
    const float* metric = (const float*)d_in[2];   // (4,1,256,448)
    float* out  = (float*)d_out;                   // (4,64,256,448)
    float* norm = (float*)d_ws;                    // N*HW floats of scratch

    // Zero accumulators (d_out and ws are poisoned 0xAA before every launch).
    hipMemsetAsync(out,  0, (size_t)N * C * HW * sizeof(float), stream);
    hipMemsetAsync(norm, 0, (size_t)N * HW * sizeof(float), stream);

    {
        int threads = 256;
        int blocks = (N * HW + threads - 1) / threads;
        splat_kernel<<<blocks, threads, 0, stream>>>(input, flow, metric, out, norm);
    }
    {
        int total = N * C * HW / 4;
        int threads = 256;
        int blocks = (total + threads - 1) / threads;
        norm_kernel<<<blocks, threads, 0, stream>>>(out, norm);
    }
}

// Round 2
// 643.529 us; speedup vs baseline: 7.4007x; 7.4007x over previous
//
#include <hip/hip_runtime.h>

constexpr int N = 4;
constexpr int C = 64;
constexpr int H = 256;
constexpr int W = 448;
constexpr int HW = H * W;

// ============================ FAST PATH =====================================
// Scratch layout: scr[(b*HW + p)*64 + c]  (NHWC, 117.4 MB)
//                 norm[b*HW + p]          (1.8 MB), after scr in d_ws.
// Wave-lane = channel ==> one wave atomic instruction hits 64 consecutive
// floats (4 cache lines) instead of 64 scattered lines.

__global__ __launch_bounds__(256) void splat_nhwc(
    const float* __restrict__ input,
    const float* __restrict__ flow,
    const float* __restrict__ metric,
    float* __restrict__ scr,     // N*HW*64 accum (pre-zeroed)
    float* __restrict__ norm)    // N*HW accum (pre-zeroed)
{
    __shared__ float s_val[256][65];   // 65 KB, pad->conflict-free transpose
    __shared__ float s_fx[256], s_fy[256], s_m[256];

    const int tid = threadIdx.x;
    const int blockPix = blockIdx.x * 256;       // HW % 256 == 0: no batch straddle
    const int b = blockPix / HW;                 // uniform per block
    const int p = (blockPix - b * HW) + tid;
    const int y = p / W;
    const int x = p - y * W;

    s_fx[tid] = (float)x + flow[(b * 2 + 0) * HW + p];
    s_fy[tid] = (float)y + flow[(b * 2 + 1) * HW + p];
    s_m[tid]  = __expf(metric[b * HW + p]);

    // Coalesced global reads (lane = pixel), transposed store into LDS.
    const float* ib = input + (size_t)b * C * HW + p;
#pragma unroll
    for (int c = 0; c < C; ++c)
        s_val[tid][c] = ib[(size_t)c * HW];

    __syncthreads();

    const int wave = tid >> 6;       // 0..3 -> which 64-pixel subset
    const int lane = tid & 63;       // channel
    float* __restrict__ sb = scr + (size_t)b * HW * 64;
    float* __restrict__ nb = norm + b * HW;

    for (int k = 0; k < 64; ++k) {
        const int j = wave * 64 + k;             // pixel within block
        const float fx = s_fx[j], fy = s_fy[j], m = s_m[j];
        const float v = s_val[j][lane] * m;

        const float x0f = floorf(fx), y0f = floorf(fy);
        const int x0 = (int)x0f, y0 = (int)y0f;
        const int x1 = x0 + 1,   y1 = y0 + 1;
        const float wx1 = fx - x0f, wx0 = 1.0f - wx1;
        const float wy1 = fy - y0f, wy0 = 1.0f - wy1;

        const bool vx0 = (x0 >= 0) & (x0 < W);
        const bool vx1 = (x1 >= 0) & (x1 < W);
        const bool vy0 = (y0 >= 0) & (y0 < H);
        const bool vy1 = (y1 >= 0) & (y1 < H);

        // All conditions are wave-uniform (j uniform across the wave).
        if (vx0 & vy0) {
            const float w = wx0 * wy0; const int t = y0 * W + x0;
            atomicAdd(sb + (size_t)t * 64 + lane, v * w);
            if (lane == 0) atomicAdd(nb + t, m * w);
        }
        if (vx1 & vy0) {
            const float w = wx1 * wy0; const int t = y0 * W + x1;
            atomicAdd(sb + (size_t)t * 64 + lane, v * w);
            if (lane == 0) atomicAdd(nb + t, m * w);
        }
        if (vx0 & vy1) {
            const float w = wx0 * wy1; const int t = y1 * W + x0;
            atomicAdd(sb + (size_t)t * 64 + lane, v * w);
            if (lane == 0) atomicAdd(nb + t, m * w);
        }
        if (vx1 & vy1) {
            const float w = wx1 * wy1; const int t = y1 * W + x1;
            atomicAdd(sb + (size_t)t * 64 + lane, v * w);
            if (lane == 0) atomicAdd(nb + t, m * w);
        }
    }
}

// NHWC scratch -> NCHW output, fused with normalization. One block per
// (batch, 64-pixel strip); LDS transpose, coalesced both directions.
__global__ __launch_bounds__(256) void untranspose_norm(
    const float* __restrict__ scr,
    const float* __restrict__ norm,
    float* __restrict__ out)
{
    __shared__ float s_t[64][65];
    __shared__ float s_inv[64];

    const int tid = threadIdx.x;
    const int strips = HW / 64;                  // 1792
    const int b = blockIdx.x / strips;
    const int pblk = (blockIdx.x - b * strips) * 64;

    if (tid < 64) {
        float n = norm[b * HW + pblk + tid];
        s_inv[tid] = (n == 0.0f) ? 1.0f : (1.0f / n);
    }

    // Read NHWC: tid maps linearly onto (pixel, channel) -> 4 KB contiguous/pass.
    const float* sb = scr + ((size_t)b * HW + pblk) * 64;
#pragma unroll
    for (int r = 0; r < 16; ++r) {
        const int pr = r * 4 + (tid >> 6);
        const int c  = tid & 63;
        s_t[pr][c] = sb[(size_t)pr * 64 + c];
    }
    __syncthreads();

    // Write NCHW: lanes = consecutive pixels -> coalesced 256B/wave.
    float* ob = out + (size_t)b * C * HW + pblk;
#pragma unroll
    for (int r = 0; r < 16; ++r) {
        const int c   = r * 4 + (tid >> 6);
        const int pix = tid & 63;
        ob[(size_t)c * HW + pix] = s_t[pix][c] * s_inv[pix];
    }
}

// ============================ FALLBACK (R1) =================================
__global__ void splat_kernel(const float* __restrict__ input,
                             const float* __restrict__ flow,
                             const float* __restrict__ metric,
                             float* __restrict__ out,
                             float* __restrict__ norm)
{
    int idx = blockIdx.x * blockDim.x + threadIdx.x;
    if (idx >= N * HW) return;
    int b = idx / HW;
    int p = idx - b * HW;
    int y = p / W;
    int x = p - y * W;

    float fx = (float)x + flow[(b * 2 + 0) * HW + p];
    float fy = (float)y + flow[(b * 2 + 1) * HW + p];
    float m  = __expf(metric[b * HW + p]);

    float x0f = floorf(fx), y0f = floorf(fy);
    int x0 = (int)x0f, y0 = (int)y0f;
    int x1 = x0 + 1,   y1 = y0 + 1;
    float wx1 = fx - x0f, wx0 = 1.0f - wx1;
    float wy1 = fy - y0f, wy0 = 1.0f - wy1;

    bool vx0 = (x0 >= 0) & (x0 < W);
    bool vx1 = (x1 >= 0) & (x1 < W);
    bool vy0 = (y0 >= 0) & (y0 < H);
    bool vy1 = (y1 >= 0) & (y1 < H);

    bool vNW = vx0 & vy0, vNE = vx1 & vy0, vSW = vx0 & vy1, vSE = vx1 & vy1;
    float wNW = wx0 * wy0, wNE = wx1 * wy0, wSW = wx0 * wy1, wSE = wx1 * wy1;
    int iNW = y0 * W + x0, iNE = y0 * W + x1, iSW = y1 * W + x0, iSE = y1 * W + x1;

    {
        float* nb = norm + b * HW;
        if (vNW) atomicAdd(nb + iNW, m * wNW);
        if (vNE) atomicAdd(nb + iNE, m * wNE);
        if (vSW) atomicAdd(nb + iSW, m * wSW);
        if (vSE) atomicAdd(nb + iSE, m * wSE);
    }

    const float* ib = input + (size_t)b * C * HW + p;
    float* ob = out + (size_t)b * C * HW;
#pragma unroll 4
    for (int c = 0; c < C; ++c) {
        float v = ib[(size_t)c * HW] * m;
        float* oc = ob + (size_t)c * HW;
        if (vNW) atomicAdd(oc + iNW, v * wNW);
        if (vNE) atomicAdd(oc + iNE, v * wNE);
        if (vSW) atomicAdd(oc + iSW, v * wSW);
        if (vSE) atomicAdd(oc + iSE, v * wSE);
    }
}

__global__ void norm_kernel(float* __restrict__ out,
                            const float* __restrict__ norm)
{
    int idx = blockIdx.x * blockDim.x + threadIdx.x;
    int total = N * C * HW / 4;
    if (idx >= total) return;

    int pixq = idx % (HW / 4);
    int bc   = idx / (HW / 4);
    int b    = bc / C;

    const float4* np4 = (const float4*)(norm + (size_t)b * HW);
    float4 n = np4[pixq];
    n.x = (n.x == 0.0f) ? 1.0f : n.x;
    n.y = (n.y == 0.0f) ? 1.0f : n.y;
    n.z = (n.z == 0.0f) ? 1.0f : n.z;
    n.w = (n.w == 0.0f) ? 1.0f : n.w;

    float4* o4 = (float4*)out;
    float4 v = o4[idx];
    v.x /= n.x; v.y /= n.y; v.z /= n.z; v.w /= n.w;
    o4[idx] = v;
}

// ============================================================================
extern "C" void kernel_launch(void* const* d_in, const int* in_sizes, int n_in,
                              void* d_out, int out_size, void* d_ws, size_t ws_size,
                              hipStream_t stream)
{
    const float* input  = (const float*)d_in[0];   // (4,64,256,448)
    const float* flow   = (const float*)d_in[1];   // (4,2,256,448)
    const float* metric = (const float*)d_in[2];   // (4,1,256,448)
    float* out = (float*)d_out;

    const size_t scr_elems  = (size_t)N * HW * 64;          // 117.4 MB
    const size_t norm_elems = (size_t)N * HW;               // 1.8 MB
    const size_t need = (scr_elems + norm_elems) * sizeof(float);

    if (ws_size >= need) {
        float* scr  = (float*)d_ws;
        float* norm = scr + scr_elems;
        hipMemsetAsync(scr, 0, need, stream);

        splat_nhwc<<<N * HW / 256, 256, 0, stream>>>(input, flow, metric, scr, norm);
        untranspose_norm<<<N * (HW / 64), 256, 0, stream>>>(scr, norm, out);
    } else {
        float* norm = (float*)d_ws;
        hipMemsetAsync(out,  0, (size_t)N * C * HW * sizeof(float), stream);
        hipMemsetAsync(norm, 0, (size_t)N * HW * sizeof(float), stream);

        splat_kernel<<<(N * HW + 255) / 256, 256, 0, stream>>>(input, flow, metric, out, norm);
        int total = N * C * HW / 4;
        norm_kernel<<<(total + 255) / 256, 256, 0, stream>>>(out, norm);
    }
}